// Round 11
// baseline (247.130 us; speedup 1.0000x reference)
//
#include <hip/hip_runtime.h>

// Problem constants (from reference)
#define N_NODES 20000
#define BATCH   4
#define DIN     32
#define DOUT    64
#define MSTEPS  7            // M = MAX_STEP*S + 1
#define ROW     128          // DIN*BATCH, channels per node
#define NROW    896          // ROW*MSTEPS elements per node (all m packed), bf16
#define NROWU   448          // NROW in uints
#define PLN     656          // LDS plane stride (shorts): 16 rows * 40 + 16 pad
#define NT      79           // 256-node dst tiles per support (79*256 >= 20000)
#define KB2     (2 * NT)     // coarse buckets = 158
#define CHUNK   2048         // P2 edges per block
#define SLOT    12288        // staged slot per bucket (mean 8192, +45 sigma)
#define WSLOT   3584         // csr slot per 64-node window (mean 2048 + pad, +24 sigma)
#define RGRID   (N_NODES / 4)   // spmm blocks per stream (4 nodes/block)

typedef short  short8 __attribute__((ext_vector_type(8)));
typedef float  f32x4  __attribute__((ext_vector_type(4)));

__device__ __forceinline__ unsigned short f2bf(float f) {
    unsigned u = __float_as_uint(f);
    unsigned r = u + 0x7fff + ((u >> 16) & 1);   // RNE to bf16
    return (unsigned short)(r >> 16);
}
__device__ __forceinline__ float bf_lo(unsigned p) { return __uint_as_float(p << 16); }
__device__ __forceinline__ float bf_hi(unsigned p) { return __uint_as_float(p & 0xffff0000u); }

// xs[n*896 + d*4 + b] = bf16(inputs[b*N*D + n*D + d])   (slice m=0)
// block 0 also initializes the p2 slot cursors (runs before p2 on the stream).
__global__ void transpose_in_k(const float* __restrict__ in, unsigned short* __restrict__ xs,
                               int* __restrict__ cursor) {
    int tid = blockIdx.x * 256 + threadIdx.x;
    if (blockIdx.x == 0 && threadIdx.x < KB2) cursor[threadIdx.x] = threadIdx.x * SLOT;
    if (tid >= N_NODES * ROW) return;
    int b = tid & 3;
    int d = (tid >> 2) & 31;
    int n = tid >> 7;
    xs[(size_t)n * NROW + d * 4 + b] = f2bf(in[(b * N_NODES + n) * DIN + d]);
}

// ---- CSR build: slotted two-level partition (no global scans) ----

// P2: LDS-staged partition into coarse (support, dst>>8) buckets; coalesced
// run flushes into the bucket's slot.  staged: {src|bf16val<<16, dst}
__global__ void __launch_bounds__(256) p2_part_k(const int* __restrict__ src,
                                                 const int* __restrict__ dst,
                                                 const float* __restrict__ vals,
                                                 int* __restrict__ cursor,
                                                 uint2* __restrict__ staged, int E) {
    __shared__ int lhist[KB2];
    __shared__ int lbase[KB2];
    __shared__ int gbase[KB2];
    __shared__ int sc[256];
    __shared__ uint2 buf[CHUNK];
    __shared__ unsigned short kk[CHUNK];
    int t = threadIdx.x;
    int base = blockIdx.x * CHUNK;
    int nval = min(CHUNK, 2 * E - base);
    for (int i = t; i < KB2; i += 256) lhist[i] = 0;
    __syncthreads();
    int k[CHUNK / 256], pos[CHUNK / 256];
    uint2 pay[CHUNK / 256];
#pragma unroll
    for (int j = 0; j < CHUNK / 256; ++j) {
        int i = j * 256 + t;
        int e = base + i;
        if (i < nval) {
            int s = (e >= E) ? 1 : 0;
            int d = dst[e];
            pay[j] = make_uint2((unsigned)src[e] | ((unsigned)f2bf(vals[e]) << 16),
                                (unsigned)d);
            k[j] = s * NT + (d >> 8);
            pos[j] = atomicAdd(&lhist[k[j]], 1);
        } else k[j] = -1;
    }
    __syncthreads();
    int v = (t < KB2) ? lhist[t] : 0;
    sc[t] = v;
    __syncthreads();
    for (int off = 1; off < 256; off <<= 1) {
        int a = (t >= off) ? sc[t - off] : 0;
        __syncthreads();
        sc[t] += a;
        __syncthreads();
    }
    if (t < KB2) lbase[t] = sc[t] - v;
    __syncthreads();
    if (t < KB2 && lhist[t]) gbase[t] = atomicAdd(&cursor[t], lhist[t]);
#pragma unroll
    for (int j = 0; j < CHUNK / 256; ++j) {
        if (k[j] >= 0) {
            int slot = lbase[k[j]] + pos[j];
            buf[slot] = pay[j];
            kk[slot] = (unsigned short)k[j];
        }
    }
    __syncthreads();
#pragma unroll
    for (int j = 0; j < CHUNK / 256; ++j) {
        int i = j * 256 + t;
        if (i < nval) {
            int b = kk[i];
            staged[gbase[b] + (i - lbase[b])] = buf[i];
        }
    }
}

// P3: one block per 64-node window (4 windows per bucket, grid 4*KB2).
// Rows padded to x8 with {src=0,val=0}; writes row_desc {start, padded_cnt}.
__global__ void __launch_bounds__(256) p3_fine_k(const uint2* __restrict__ staged,
                                                 const int* __restrict__ cursor,
                                                 int2* __restrict__ row_desc,
                                                 unsigned* __restrict__ csr) {
    __shared__ int lhist[64];
    __shared__ int sc[64];
    __shared__ int lcur[64];
    int bb = blockIdx.x;
    int b = bb >> 2, sub = bb & 3;
    int s = b / NT, tile = b - s * NT;
    int w0loc = sub * 64;                    // window start within tile
    int seg0 = b * SLOT;
    int len = cursor[b] - seg0;
    int t = threadIdx.x;
    if (t < 64) lhist[t] = 0;
    __syncthreads();
    for (int i = t; i < len; i += 256) {
        int dl = (int)(staged[seg0 + i].y & 255) - w0loc;
        if (dl >= 0 && dl < 64) atomicAdd(&lhist[dl], 1);
    }
    __syncthreads();
    int cntr = (t < 64) ? lhist[t] : 0;
    int pl = (cntr + 7) & ~7;
    if (t < 64) sc[t] = pl;
    __syncthreads();
    for (int off = 1; off < 64; off <<= 1) {
        int a = (t < 64 && t >= off) ? sc[t - off] : 0;
        __syncthreads();
        if (t < 64) sc[t] += a;
        __syncthreads();
    }
    int wbase = bb * WSLOT;
    if (t < 64) {
        int excl = sc[t] - pl;
        lcur[t] = wbase + excl;
        int nd = tile * 256 + w0loc + t;
        if (nd < N_NODES) row_desc[s * N_NODES + nd] = make_int2(wbase + excl, pl);
    }
    __syncthreads();
    for (int i = t; i < len; i += 256) {
        uint2 u = staged[seg0 + i];
        int dl = (int)(u.y & 255) - w0loc;
        if (dl >= 0 && dl < 64) {
            int p = atomicAdd(&lcur[dl], 1);
            csr[p] = u.x;
        }
    }
    if (t < 64) {
        int excl = sc[t] - pl;
        for (int i = cntr; i < pl; ++i) csr[wbase + excl + i] = 0u;
    }
}

// ---- SpMM gather core: PAIRED edges — lanes 0-31 fetch edge e (uint2 each),
// lanes 32-63 fetch edge e+1. Half the vmem requests, same bytes. Rows are
// multiples of 8 (padded with src=0,val=0), no tail.
__device__ __forceinline__ void spmm_core(const int2* __restrict__ rdesc,
                                          const unsigned* __restrict__ csr,
                                          const unsigned* __restrict__ xb,
                                          const unsigned* __restrict__ xprevb,
                                          unsigned* __restrict__ yb,
                                          float alpha, int node, int lane) {
    int2 rd = rdesc[node];
    int start = rd.x, end = rd.x + rd.y;
    int half = lane >> 5;         // which edge of the pair
    int sub  = lane & 31;         // uint2 chunk within the row (4 channels)
    float a0 = 0.f, a1 = 0.f, a2 = 0.f, a3 = 0.f;   // 4 channels, pairs j=0,2
    float b0 = 0.f, b1 = 0.f, b2 = 0.f, b3 = 0.f;   // pairs j=1,3
    const uint2* xb2 = (const uint2*)xb;
    for (int e = start; e < end; e += 8) {
        unsigned c0 = csr[e],     c1 = csr[e + 1], c2 = csr[e + 2], c3 = csr[e + 3];
        unsigned c4 = csr[e + 4], c5 = csr[e + 5], c6 = csr[e + 6], c7 = csr[e + 7];
        unsigned s0 = half ? (c1 & 0xffffu) : (c0 & 0xffffu);
        unsigned s1 = half ? (c3 & 0xffffu) : (c2 & 0xffffu);
        unsigned s2 = half ? (c5 & 0xffffu) : (c4 & 0xffffu);
        unsigned s3 = half ? (c7 & 0xffffu) : (c6 & 0xffffu);
        uint2 p0 = xb2[(size_t)s0 * (NROWU / 2) + sub];
        uint2 p1 = xb2[(size_t)s1 * (NROWU / 2) + sub];
        uint2 p2 = xb2[(size_t)s2 * (NROWU / 2) + sub];
        uint2 p3 = xb2[(size_t)s3 * (NROWU / 2) + sub];
        float v0 = half ? bf_hi(c1) : bf_hi(c0);
        float v1 = half ? bf_hi(c3) : bf_hi(c2);
        float v2 = half ? bf_hi(c5) : bf_hi(c4);
        float v3 = half ? bf_hi(c7) : bf_hi(c6);
        a0 = fmaf(v0, bf_lo(p0.x), a0);  a1 = fmaf(v0, bf_hi(p0.x), a1);
        a2 = fmaf(v0, bf_lo(p0.y), a2);  a3 = fmaf(v0, bf_hi(p0.y), a3);
        b0 = fmaf(v1, bf_lo(p1.x), b0);  b1 = fmaf(v1, bf_hi(p1.x), b1);
        b2 = fmaf(v1, bf_lo(p1.y), b2);  b3 = fmaf(v1, bf_hi(p1.y), b3);
        a0 = fmaf(v2, bf_lo(p2.x), a0);  a1 = fmaf(v2, bf_hi(p2.x), a1);
        a2 = fmaf(v2, bf_lo(p2.y), a2);  a3 = fmaf(v2, bf_hi(p2.y), a3);
        b0 = fmaf(v3, bf_lo(p3.x), b0);  b1 = fmaf(v3, bf_hi(p3.x), b1);
        b2 = fmaf(v3, bf_lo(p3.y), b2);  b3 = fmaf(v3, bf_hi(p3.y), b3);
    }
    float r0 = a0 + b0, r1 = a1 + b1, r2 = a2 + b2, r3 = a3 + b3;
    // cross-half combine: partner lane (lane^32) holds the other edges' sums
    r0 += __shfl_xor(r0, 32, 64);
    r1 += __shfl_xor(r1, 32, 64);
    r2 += __shfl_xor(r2, 32, 64);
    r3 += __shfl_xor(r3, 32, 64);
    r0 *= alpha; r1 *= alpha; r2 *= alpha; r3 *= alpha;
    if (xprevb) {
        uint2 pp = ((const uint2*)xprevb)[(size_t)node * (NROWU / 2) + sub];
        r0 -= bf_lo(pp.x);
        r1 -= bf_hi(pp.x);
        r2 -= bf_lo(pp.y);
        r3 -= bf_hi(pp.y);
    }
    if (half == 0) {
        uint2 po;
        po.x = (unsigned)f2bf(r0) | ((unsigned)f2bf(r1) << 16);
        po.y = (unsigned)f2bf(r2) | ((unsigned)f2bf(r3) << 16);
        ((uint2*)yb)[(size_t)node * (NROWU / 2) + sub] = po;
    }
}

__global__ void __launch_bounds__(256) spmm_row_k(const int2* __restrict__ rdesc,
                                                  const unsigned* __restrict__ csr,
                                                  const unsigned short* __restrict__ x,
                                                  const unsigned short* __restrict__ xprev,
                                                  unsigned short* __restrict__ y, float alpha) {
    int node = __builtin_amdgcn_readfirstlane(blockIdx.x * 4 + (threadIdx.x >> 6));
    int lane = threadIdx.x & 63;
    spmm_core(rdesc, csr, (const unsigned*)x, (const unsigned*)xprev, (unsigned*)y,
              alpha, node, lane);
}

// dual dispatch: blocks [0,RGRID) A-stream, [RGRID,2*RGRID) B-stream, same input x.
// x3 = 2*A0*x2 - x1 ; x4 = A1*x2.
__global__ void __launch_bounds__(256) spmm_dual_k(const int2* __restrict__ rdA,
                                                   const int2* __restrict__ rdB,
                                                   const unsigned* __restrict__ csr,
                                                   const unsigned short* __restrict__ x,
                                                   const unsigned short* __restrict__ xprevA,
                                                   unsigned short* __restrict__ yA,
                                                   unsigned short* __restrict__ yB) {
    int bid = blockIdx.x;
    int second = (bid >= RGRID) ? 1 : 0;
    int node = __builtin_amdgcn_readfirstlane((bid - second * RGRID) * 4 + (threadIdx.x >> 6));
    int lane = threadIdx.x & 63;
    const int2* rd = second ? rdB : rdA;
    const unsigned* xprevb = second ? nullptr : (const unsigned*)xprevA;
    unsigned* yb = second ? (unsigned*)yB : (unsigned*)yA;
    float alpha = second ? 1.0f : 2.0f;
    spmm_core(rd, csr, (const unsigned*)x, xprevb, yb, alpha, node, lane);
}

// ---- MFMA epilogue (unchanged — verified correct) ----
__global__ void __launch_bounds__(256) epilogue_mfma_k(const unsigned short* __restrict__ xs,
                                                       const float* __restrict__ W,
                                                       const float* __restrict__ bias,
                                                       float* __restrict__ out) {
    __shared__ unsigned short Alds[28 * PLN];   // 36736 B
    int tid = threadIdx.x;
    int lane = tid & 63, ot = tid >> 6;
    int col = lane & 15, quad = lane >> 4;
    int o = ot * 16 + col;

    short8 bfrag[MSTEPS];
#pragma unroll
    for (int m = 0; m < MSTEPS; ++m) {
        short8 bf;
#pragma unroll
        for (int j = 0; j < 8; ++j)
            bf[j] = (short)f2bf(W[o * 224 + (quad * 8 + j) * 7 + m]);
        bfrag[m] = bf;
    }
    float bo = bias[o];

    int n0 = blockIdx.x * 16;
    const uint4* src = (const uint4*)(xs + (size_t)n0 * NROW);   // 1792 uint4
#pragma unroll
    for (int it = 0; it < 7; ++it) {
        int idx = tid + it * 256;
        uint4 q = src[idx];
        int r    = idx / 112;            // node row 0..15
        int off8 = idx - r * 112;        // element-octet within row
        int m    = off8 >> 4;
        int d0   = (off8 & 15) * 2;
        unsigned vals[4] = {q.x, q.y, q.z, q.w};
#pragma unroll
        for (int h = 0; h < 4; ++h) {
            int dd = d0 + (h >> 1);
            int bA = (2 * h) & 3, bB = (2 * h + 1) & 3;
            Alds[(bA * 7 + m) * PLN + r * 40 + dd] = (unsigned short)(vals[h] & 0xffffu);
            Alds[(bB * 7 + m) * PLN + r * 40 + dd] = (unsigned short)(vals[h] >> 16);
        }
    }
    __syncthreads();

    f32x4 acc[BATCH];
#pragma unroll
    for (int b = 0; b < BATCH; ++b)
        acc[b] = (f32x4){bo, bo, bo, bo};

#pragma unroll
    for (int m = 0; m < MSTEPS; ++m) {
#pragma unroll
        for (int b = 0; b < BATCH; ++b) {
            short8 a = *(const short8*)&Alds[(b * 7 + m) * PLN + col * 40 + quad * 8];
            acc[b] = __builtin_amdgcn_mfma_f32_16x16x32_bf16(a, bfrag[m], acc[b], 0, 0, 0);
        }
    }

#pragma unroll
    for (int b = 0; b < BATCH; ++b) {
#pragma unroll
        for (int reg = 0; reg < 4; ++reg) {
            int n = n0 + quad * 4 + reg;
            out[((size_t)b * N_NODES + n) * DOUT + o] = acc[b][reg];
        }
    }
}

extern "C" void kernel_launch(void* const* d_in, const int* in_sizes, int n_in,
                              void* d_out, int out_size, void* d_ws, size_t ws_size,
                              hipStream_t stream) {
    const float* inputs    = (const float*)d_in[0];
    const float* edge_vals = (const float*)d_in[1];
    const float* W         = (const float*)d_in[2];
    const float* bias      = (const float*)d_in[3];
    const int*   edge_src  = (const int*)d_in[4];
    const int*   edge_dst  = (const int*)d_in[5];
    float* out = (float*)d_out;
    const int E = in_sizes[1] / 2;   // edges per support

    unsigned short* xs = (unsigned short*)d_ws;                    // 35.84 MB
    uint2* staged  = (uint2*)(xs + (size_t)N_NODES * NROW);        // KB2*SLOT*8 = 15.5 MB
    unsigned* csr  = (unsigned*)(staged + (size_t)KB2 * SLOT);     // 4*KB2*WSLOT*4 = 9.1 MB
    int* cursor    = (int*)(csr + (size_t)4 * KB2 * WSLOT);        // KB2
    int2* row_desc = (int2*)(cursor + KB2 + 2);                    // 2*N int2

    const int tgrid  = (N_NODES * ROW + 255) / 256;
    const int pgrid  = (2 * E + CHUNK - 1) / CHUNK;    // 625
    const int epgrid = N_NODES / 16;

    // transpose (also inits p2 cursors; ordered before p2 on the stream)
    transpose_in_k<<<tgrid, 256, 0, stream>>>(inputs, xs, cursor);

    // ---- CSR build: partition -> fine (no global scans) ----
    p2_part_k<<<pgrid, 256, 0, stream>>>(edge_src, edge_dst, edge_vals, cursor, staged, E);
    p3_fine_k<<<4 * KB2, 256, 0, stream>>>(staged, cursor, row_desc, csr);

    const int2* rd0 = row_desc;
    const int2* rd1 = row_desc + N_NODES;

    // xs_m slice base = xs + m*128 (node stride NROW elements)
    unsigned short* X0 = xs + 0 * ROW;
    unsigned short* X1 = xs + 1 * ROW;
    unsigned short* X2 = xs + 2 * ROW;
    unsigned short* X3 = xs + 3 * ROW;
    unsigned short* X4 = xs + 4 * ROW;
    unsigned short* X5 = xs + 5 * ROW;
    unsigned short* X6 = xs + 6 * ROW;

    // support 0: xs1 = A0 x0 ; xs2 = 2 A0 xs1 - xs0
    spmm_row_k<<<RGRID, 256, 0, stream>>>(rd0, csr, X0, nullptr, X1, 1.0f);
    spmm_row_k<<<RGRID, 256, 0, stream>>>(rd0, csr, X1, X0,      X2, 2.0f);
    // xs3 = 2 A0 xs2 - xs1  ||  xs4 = A1 xs2   (independent; merged dispatch)
    spmm_dual_k<<<2 * RGRID, 256, 0, stream>>>(rd0, rd1, csr, X2, X1, X3, X4);
    // support 1 tail: xs5 = 2 A1 xs4 - xs2 ; xs6 = 2 A1 xs5 - xs4
    spmm_row_k<<<RGRID, 256, 0, stream>>>(rd1, csr, X4, X2, X5, 2.0f);
    spmm_row_k<<<RGRID, 256, 0, stream>>>(rd1, csr, X5, X4, X6, 2.0f);

    epilogue_mfma_k<<<epgrid, 256, 0, stream>>>(xs, W, bias, out);
}

// Round 12
// 236.926 us; speedup vs baseline: 1.0431x; 1.0431x over previous
//
#include <hip/hip_runtime.h>

// Problem constants (from reference)
#define N_NODES 20000
#define BATCH   4
#define DIN     32
#define DOUT    64
#define MSTEPS  7            // M = MAX_STEP*S + 1
#define ROW     128          // DIN*BATCH, channels per node
#define NROW    896          // ROW*MSTEPS elements per node (all m packed), bf16
#define NROWU   448          // NROW in uints
#define PLN     656          // LDS plane stride (shorts): 16 rows * 40 + 16 pad
#define NT      79           // 256-node dst tiles per support (79*256 >= 20000)
#define KB2     (2 * NT)     // coarse buckets = 158
#define CHUNK   2048         // P2 edges per block
#define SLOT    12288        // staged slot per bucket (mean 8192, +45 sigma)
#define WSLOT   3584         // csr slot per 64-node window (mean 2048 + pad, +24 sigma)
#define RGRID   (N_NODES / 4)   // spmm blocks per stream (4 nodes/block)
#define PGRID   625             // ceil(2E / CHUNK) for E=640000
#define TGRID   10000           // ceil(N*ROW / 256)

typedef short  short8 __attribute__((ext_vector_type(8)));
typedef float  f32x4  __attribute__((ext_vector_type(4)));

__device__ __forceinline__ unsigned short f2bf(float f) {
    unsigned u = __float_as_uint(f);
    unsigned r = u + 0x7fff + ((u >> 16) & 1);   // RNE to bf16
    return (unsigned short)(r >> 16);
}
__device__ __forceinline__ float bf_lo(unsigned p) { return __uint_as_float(p << 16); }
__device__ __forceinline__ float bf_hi(unsigned p) { return __uint_as_float(p & 0xffff0000u); }

// slot-cursor init (must precede the fused partition kernel)
__global__ void init_k(int* __restrict__ cursor) {
    if (threadIdx.x < KB2) cursor[threadIdx.x] = threadIdx.x * SLOT;
}

// ---- Fused P2-partition + input-transpose (disjoint block ranges overlap) ----
// blocks [0,PGRID): LDS-staged partition of edges into coarse (s, dst>>8)
//   bucket slots; staged entry {src|bf16val<<16, dst}.
// blocks [PGRID, PGRID+TGRID): xs[n*896 + d*4 + b] = bf16(in[b,n,d]) (slice m=0)
__global__ void __launch_bounds__(256) p2t_k(const int* __restrict__ src,
                                             const int* __restrict__ dst,
                                             const float* __restrict__ vals,
                                             int* __restrict__ cursor,
                                             uint2* __restrict__ staged,
                                             const float* __restrict__ in,
                                             unsigned short* __restrict__ xs, int E) {
    __shared__ int lhist[KB2];
    __shared__ int lbase[KB2];
    __shared__ int gbase[KB2];
    __shared__ int sc[256];
    __shared__ uint2 buf[CHUNK];
    __shared__ unsigned short kk[CHUNK];
    int t = threadIdx.x;
    if (blockIdx.x >= PGRID) {
        // transpose branch
        int tid = (blockIdx.x - PGRID) * 256 + t;
        if (tid < N_NODES * ROW) {
            int b = tid & 3;
            int d = (tid >> 2) & 31;
            int n = tid >> 7;
            xs[(size_t)n * NROW + d * 4 + b] = f2bf(in[(b * N_NODES + n) * DIN + d]);
        }
        return;
    }
    int base = blockIdx.x * CHUNK;
    int nval = min(CHUNK, 2 * E - base);
    for (int i = t; i < KB2; i += 256) lhist[i] = 0;
    __syncthreads();
    int k[CHUNK / 256], pos[CHUNK / 256];
    uint2 pay[CHUNK / 256];
#pragma unroll
    for (int j = 0; j < CHUNK / 256; ++j) {
        int i = j * 256 + t;
        int e = base + i;
        if (i < nval) {
            int s = (e >= E) ? 1 : 0;
            int d = dst[e];
            pay[j] = make_uint2((unsigned)src[e] | ((unsigned)f2bf(vals[e]) << 16),
                                (unsigned)d);
            k[j] = s * NT + (d >> 8);
            pos[j] = atomicAdd(&lhist[k[j]], 1);
        } else k[j] = -1;
    }
    __syncthreads();
    int v = (t < KB2) ? lhist[t] : 0;
    sc[t] = v;
    __syncthreads();
    for (int off = 1; off < 256; off <<= 1) {
        int a = (t >= off) ? sc[t - off] : 0;
        __syncthreads();
        sc[t] += a;
        __syncthreads();
    }
    if (t < KB2) lbase[t] = sc[t] - v;
    __syncthreads();
    if (t < KB2 && lhist[t]) gbase[t] = atomicAdd(&cursor[t], lhist[t]);
#pragma unroll
    for (int j = 0; j < CHUNK / 256; ++j) {
        if (k[j] >= 0) {
            int slot = lbase[k[j]] + pos[j];
            buf[slot] = pay[j];
            kk[slot] = (unsigned short)k[j];
        }
    }
    __syncthreads();
#pragma unroll
    for (int j = 0; j < CHUNK / 256; ++j) {
        int i = j * 256 + t;
        if (i < nval) {
            int b = kk[i];
            staged[gbase[b] + (i - lbase[b])] = buf[i];
        }
    }
}

// P3: one block per 64-node window (4 windows per bucket, grid 4*KB2).
// Rows padded to x8 with {src=0,val=0}; writes row_desc {start, padded_cnt}.
__global__ void __launch_bounds__(256) p3_fine_k(const uint2* __restrict__ staged,
                                                 const int* __restrict__ cursor,
                                                 int2* __restrict__ row_desc,
                                                 unsigned* __restrict__ csr) {
    __shared__ int lhist[64];
    __shared__ int sc[64];
    __shared__ int lcur[64];
    int bb = blockIdx.x;
    int b = bb >> 2, sub = bb & 3;
    int s = b / NT, tile = b - s * NT;
    int w0loc = sub * 64;                    // window start within tile
    int seg0 = b * SLOT;
    int len = cursor[b] - seg0;
    int t = threadIdx.x;
    if (t < 64) lhist[t] = 0;
    __syncthreads();
    for (int i = t; i < len; i += 256) {
        int dl = (int)(staged[seg0 + i].y & 255) - w0loc;
        if (dl >= 0 && dl < 64) atomicAdd(&lhist[dl], 1);
    }
    __syncthreads();
    int cntr = (t < 64) ? lhist[t] : 0;
    int pl = (cntr + 7) & ~7;
    if (t < 64) sc[t] = pl;
    __syncthreads();
    for (int off = 1; off < 64; off <<= 1) {
        int a = (t < 64 && t >= off) ? sc[t - off] : 0;
        __syncthreads();
        if (t < 64) sc[t] += a;
        __syncthreads();
    }
    int wbase = bb * WSLOT;
    if (t < 64) {
        int excl = sc[t] - pl;
        lcur[t] = wbase + excl;
        int nd = tile * 256 + w0loc + t;
        if (nd < N_NODES) row_desc[s * N_NODES + nd] = make_int2(wbase + excl, pl);
    }
    __syncthreads();
    for (int i = t; i < len; i += 256) {
        uint2 u = staged[seg0 + i];
        int dl = (int)(u.y & 255) - w0loc;
        if (dl >= 0 && dl < 64) {
            int p = atomicAdd(&lcur[dl], 1);
            csr[p] = u.x;
        }
    }
    if (t < 64) {
        int excl = sc[t] - pl;
        for (int i = cntr; i < pl; ++i) csr[wbase + excl + i] = 0u;
    }
}

// ---- SpMM gather core (R9-verified): rows are multiples of 8, no tail ----
__device__ __forceinline__ void spmm_core(const int2* __restrict__ rdesc,
                                          const unsigned* __restrict__ csr,
                                          const unsigned* __restrict__ xb,
                                          const unsigned* __restrict__ xprevb,
                                          unsigned* __restrict__ yb,
                                          float alpha, int node, int lane) {
    int2 rd = rdesc[node];
    int start = rd.x, end = rd.x + rd.y;
    float l0 = 0.f, h0 = 0.f, l1 = 0.f, h1 = 0.f;
    float l2 = 0.f, h2 = 0.f, l3 = 0.f, h3 = 0.f;
    for (int e = start; e < end; e += 8) {
        unsigned c0 = csr[e],     c1 = csr[e + 1], c2 = csr[e + 2], c3 = csr[e + 3];
        unsigned c4 = csr[e + 4], c5 = csr[e + 5], c6 = csr[e + 6], c7 = csr[e + 7];
        unsigned p0 = xb[(size_t)(c0 & 0xffffu) * NROWU + lane];
        unsigned p1 = xb[(size_t)(c1 & 0xffffu) * NROWU + lane];
        unsigned p2 = xb[(size_t)(c2 & 0xffffu) * NROWU + lane];
        unsigned p3 = xb[(size_t)(c3 & 0xffffu) * NROWU + lane];
        unsigned p4 = xb[(size_t)(c4 & 0xffffu) * NROWU + lane];
        unsigned p5 = xb[(size_t)(c5 & 0xffffu) * NROWU + lane];
        unsigned p6 = xb[(size_t)(c6 & 0xffffu) * NROWU + lane];
        unsigned p7 = xb[(size_t)(c7 & 0xffffu) * NROWU + lane];
        float v0 = bf_hi(c0), v1 = bf_hi(c1), v2 = bf_hi(c2), v3 = bf_hi(c3);
        float v4 = bf_hi(c4), v5 = bf_hi(c5), v6 = bf_hi(c6), v7 = bf_hi(c7);
        l0 = fmaf(v0, bf_lo(p0), l0);  h0 = fmaf(v0, bf_hi(p0), h0);
        l1 = fmaf(v1, bf_lo(p1), l1);  h1 = fmaf(v1, bf_hi(p1), h1);
        l2 = fmaf(v2, bf_lo(p2), l2);  h2 = fmaf(v2, bf_hi(p2), h2);
        l3 = fmaf(v3, bf_lo(p3), l3);  h3 = fmaf(v3, bf_hi(p3), h3);
        l0 = fmaf(v4, bf_lo(p4), l0);  h0 = fmaf(v4, bf_hi(p4), h0);
        l1 = fmaf(v5, bf_lo(p5), l1);  h1 = fmaf(v5, bf_hi(p5), h1);
        l2 = fmaf(v6, bf_lo(p6), l2);  h2 = fmaf(v6, bf_hi(p6), h2);
        l3 = fmaf(v7, bf_lo(p7), l3);  h3 = fmaf(v7, bf_hi(p7), h3);
    }
    float r0 = alpha * ((l0 + l1) + (l2 + l3));
    float r1 = alpha * ((h0 + h1) + (h2 + h3));
    if (xprevb) {
        unsigned pp = xprevb[(size_t)node * NROWU + lane];
        r0 -= bf_lo(pp);
        r1 -= bf_hi(pp);
    }
    yb[(size_t)node * NROWU + lane] = (unsigned)f2bf(r0) | ((unsigned)f2bf(r1) << 16);
}

__global__ void __launch_bounds__(256) spmm_row_k(const int2* __restrict__ rdesc,
                                                  const unsigned* __restrict__ csr,
                                                  const unsigned short* __restrict__ x,
                                                  const unsigned short* __restrict__ xprev,
                                                  unsigned short* __restrict__ y, float alpha) {
    int node = __builtin_amdgcn_readfirstlane(blockIdx.x * 4 + (threadIdx.x >> 6));
    int lane = threadIdx.x & 63;
    spmm_core(rdesc, csr, (const unsigned*)x, (const unsigned*)xprev, (unsigned*)y,
              alpha, node, lane);
}

// dual dispatch: blocks [0,RGRID) A-stream, [RGRID,2*RGRID) B-stream, same input x.
// x3 = 2*A0*x2 - x1 ; x4 = A1*x2.
__global__ void __launch_bounds__(256) spmm_dual_k(const int2* __restrict__ rdA,
                                                   const int2* __restrict__ rdB,
                                                   const unsigned* __restrict__ csr,
                                                   const unsigned short* __restrict__ x,
                                                   const unsigned short* __restrict__ xprevA,
                                                   unsigned short* __restrict__ yA,
                                                   unsigned short* __restrict__ yB) {
    int bid = blockIdx.x;
    int second = (bid >= RGRID) ? 1 : 0;
    int node = __builtin_amdgcn_readfirstlane((bid - second * RGRID) * 4 + (threadIdx.x >> 6));
    int lane = threadIdx.x & 63;
    const int2* rd = second ? rdB : rdA;
    const unsigned* xprevb = second ? nullptr : (const unsigned*)xprevA;
    unsigned* yb = second ? (unsigned*)yB : (unsigned*)yA;
    float alpha = second ? 1.0f : 2.0f;
    spmm_core(rd, csr, (const unsigned*)x, xprevb, yb, alpha, node, lane);
}

// ---- MFMA epilogue (unchanged — verified correct) ----
__global__ void __launch_bounds__(256) epilogue_mfma_k(const unsigned short* __restrict__ xs,
                                                       const float* __restrict__ W,
                                                       const float* __restrict__ bias,
                                                       float* __restrict__ out) {
    __shared__ unsigned short Alds[28 * PLN];   // 36736 B
    int tid = threadIdx.x;
    int lane = tid & 63, ot = tid >> 6;
    int col = lane & 15, quad = lane >> 4;
    int o = ot * 16 + col;

    short8 bfrag[MSTEPS];
#pragma unroll
    for (int m = 0; m < MSTEPS; ++m) {
        short8 bf;
#pragma unroll
        for (int j = 0; j < 8; ++j)
            bf[j] = (short)f2bf(W[o * 224 + (quad * 8 + j) * 7 + m]);
        bfrag[m] = bf;
    }
    float bo = bias[o];

    int n0 = blockIdx.x * 16;
    const uint4* src = (const uint4*)(xs + (size_t)n0 * NROW);   // 1792 uint4
#pragma unroll
    for (int it = 0; it < 7; ++it) {
        int idx = tid + it * 256;
        uint4 q = src[idx];
        int r    = idx / 112;            // node row 0..15
        int off8 = idx - r * 112;        // element-octet within row
        int m    = off8 >> 4;
        int d0   = (off8 & 15) * 2;
        unsigned vals[4] = {q.x, q.y, q.z, q.w};
#pragma unroll
        for (int h = 0; h < 4; ++h) {
            int dd = d0 + (h >> 1);
            int bA = (2 * h) & 3, bB = (2 * h + 1) & 3;
            Alds[(bA * 7 + m) * PLN + r * 40 + dd] = (unsigned short)(vals[h] & 0xffffu);
            Alds[(bB * 7 + m) * PLN + r * 40 + dd] = (unsigned short)(vals[h] >> 16);
        }
    }
    __syncthreads();

    f32x4 acc[BATCH];
#pragma unroll
    for (int b = 0; b < BATCH; ++b)
        acc[b] = (f32x4){bo, bo, bo, bo};

#pragma unroll
    for (int m = 0; m < MSTEPS; ++m) {
#pragma unroll
        for (int b = 0; b < BATCH; ++b) {
            short8 a = *(const short8*)&Alds[(b * 7 + m) * PLN + col * 40 + quad * 8];
            acc[b] = __builtin_amdgcn_mfma_f32_16x16x32_bf16(a, bfrag[m], acc[b], 0, 0, 0);
        }
    }

#pragma unroll
    for (int b = 0; b < BATCH; ++b) {
#pragma unroll
        for (int reg = 0; reg < 4; ++reg) {
            int n = n0 + quad * 4 + reg;
            out[((size_t)b * N_NODES + n) * DOUT + o] = acc[b][reg];
        }
    }
}

extern "C" void kernel_launch(void* const* d_in, const int* in_sizes, int n_in,
                              void* d_out, int out_size, void* d_ws, size_t ws_size,
                              hipStream_t stream) {
    const float* inputs    = (const float*)d_in[0];
    const float* edge_vals = (const float*)d_in[1];
    const float* W         = (const float*)d_in[2];
    const float* bias      = (const float*)d_in[3];
    const int*   edge_src  = (const int*)d_in[4];
    const int*   edge_dst  = (const int*)d_in[5];
    float* out = (float*)d_out;
    const int E = in_sizes[1] / 2;   // edges per support

    unsigned short* xs = (unsigned short*)d_ws;                    // 35.84 MB
    uint2* staged  = (uint2*)(xs + (size_t)N_NODES * NROW);        // KB2*SLOT*8 = 15.5 MB
    unsigned* csr  = (unsigned*)(staged + (size_t)KB2 * SLOT);     // 4*KB2*WSLOT*4 = 9.1 MB
    int* cursor    = (int*)(csr + (size_t)4 * KB2 * WSLOT);        // KB2
    int2* row_desc = (int2*)(cursor + KB2 + 2);                    // 2*N int2

    const int epgrid = N_NODES / 16;

    // ---- CSR build + transpose: init -> fused(partition || transpose) -> fine ----
    init_k<<<1, 256, 0, stream>>>(cursor);
    p2t_k<<<PGRID + TGRID, 256, 0, stream>>>(edge_src, edge_dst, edge_vals, cursor,
                                             staged, inputs, xs, E);
    p3_fine_k<<<4 * KB2, 256, 0, stream>>>(staged, cursor, row_desc, csr);

    const int2* rd0 = row_desc;
    const int2* rd1 = row_desc + N_NODES;

    // xs_m slice base = xs + m*128 (node stride NROW elements)
    unsigned short* X0 = xs + 0 * ROW;
    unsigned short* X1 = xs + 1 * ROW;
    unsigned short* X2 = xs + 2 * ROW;
    unsigned short* X3 = xs + 3 * ROW;
    unsigned short* X4 = xs + 4 * ROW;
    unsigned short* X5 = xs + 5 * ROW;
    unsigned short* X6 = xs + 6 * ROW;

    // support 0: xs1 = A0 x0 ; xs2 = 2 A0 xs1 - xs0
    spmm_row_k<<<RGRID, 256, 0, stream>>>(rd0, csr, X0, nullptr, X1, 1.0f);
    spmm_row_k<<<RGRID, 256, 0, stream>>>(rd0, csr, X1, X0,      X2, 2.0f);
    // xs3 = 2 A0 xs2 - xs1  ||  xs4 = A1 xs2   (independent; merged dispatch)
    spmm_dual_k<<<2 * RGRID, 256, 0, stream>>>(rd0, rd1, csr, X2, X1, X3, X4);
    // support 1 tail: xs5 = 2 A1 xs4 - xs2 ; xs6 = 2 A1 xs5 - xs4
    spmm_row_k<<<RGRID, 256, 0, stream>>>(rd1, csr, X4, X2, X5, 2.0f);
    spmm_row_k<<<RGRID, 256, 0, stream>>>(rd1, csr, X5, X4, X6, 2.0f);

    epilogue_mfma_k<<<epgrid, 256, 0, stream>>>(xs, W, bias, out);
}